// Round 1
// baseline (477.854 us; speedup 1.0000x reference)
//
#include <hip/hip_runtime.h>
#include <hip/hip_bf16.h>

typedef unsigned short u16;
typedef __bf16 bf16x8 __attribute__((ext_vector_type(8)));
typedef float f32x4 __attribute__((ext_vector_type(4)));

#define H_DIM 2048
#define I_DIM 1408
#define T_TOK 1024
#define NEXP 8
#define LS 40  // fallback-path LDS stride

__device__ __forceinline__ u16 f2bf(float f) {
    union { float f; unsigned u; } v; v.f = f;
    unsigned r = v.u + 0x7FFFu + ((v.u >> 16) & 1u);  // RNE
    return (u16)(r >> 16);
}
__device__ __forceinline__ unsigned pack2(float a, float b) {
    float2 t; t.x = a; t.y = b;
    __hip_bfloat162 h = __float22bfloat162_rn(t);  // v_cvt_pk_bf16_f32
    union { __hip_bfloat162 h; unsigned u; } v; v.h = h;
    return v.u;
}
__device__ __forceinline__ uint2 pack4(float4 f) {
    uint2 r; r.x = pack2(f.x, f.y); r.y = pack2(f.z, f.w); return r;
}
__device__ __forceinline__ void g2l16(const void* g, void* l) {
    __builtin_amdgcn_global_load_lds((const __attribute__((address_space(1))) void*)g,
                                     (__attribute__((address_space(3))) void*)l, 16, 0, 0);
}

// ============ prep1: convert gate/up weights (lane-contiguous) + router/x-convert ============
// blocks 0..1583: weight convert (egw 704, euw 704, sgw 88, suw 88; 8192 float4 per block)
// blocks 1584..1839: router (4 tokens/block)
struct Prep1Args {
    const float* src[4]; u16* dst[4];
    const float* x; const float* gw; u16* xb;
    int* counts; int* tok; float* tw; unsigned* tslot;
};

__global__ __launch_bounds__(256)
void prep1_kernel(Prep1Args a) {
    int b = blockIdx.x;
    if (b < 1584) {
        int r, rb;
        if (b < 704)       { r = 0; rb = b; }
        else if (b < 1408) { r = 1; rb = b - 704; }
        else if (b < 1496) { r = 2; rb = b - 1408; }
        else               { r = 3; rb = b - 1496; }
        const float4* in = (const float4*)a.src[r];
        uint2* out = (uint2*)a.dst[r];
        size_t base = (size_t)rb * 8192 + threadIdx.x;
#pragma unroll
        for (int it = 0; it < 4; it++) {
            float4 v[8];
#pragma unroll
            for (int j = 0; j < 8; j++) v[j] = in[base + it * 2048 + j * 256];
#pragma unroll
            for (int j = 0; j < 8; j++) out[base + it * 2048 + j * 256] = pack4(v[j]);
        }
    } else {
        int wave = threadIdx.x >> 6, lane = threadIdx.x & 63;
        int t = (b - 1584) * 4 + wave;
        const float4* xr = (const float4*)(a.x + (size_t)t * H_DIM);
        const float4* gw4 = (const float4*)a.gw;
        uint2* xbr = (uint2*)(a.xb + (size_t)t * H_DIM);
        float acc[NEXP];
#pragma unroll
        for (int e = 0; e < NEXP; e++) acc[e] = 0.f;
#pragma unroll
        for (int j = 0; j < 8; j++) {
            int c = lane + j * 64;
            float4 xv = xr[c];
            xbr[c] = pack4(xv);
#pragma unroll
            for (int e = 0; e < NEXP; e++) {
                float4 gv = gw4[e * 512 + c];
                acc[e] += xv.x * gv.x + xv.y * gv.y + xv.z * gv.z + xv.w * gv.w;
            }
        }
#pragma unroll
        for (int e = 0; e < NEXP; e++) {
#pragma unroll
            for (int off = 32; off > 0; off >>= 1) acc[e] += __shfl_xor(acc[e], off);
        }
        if (lane == 0) {
            int i0 = 0; float v0 = acc[0];
#pragma unroll
            for (int e = 1; e < NEXP; e++) if (acc[e] > v0) { v0 = acc[e]; i0 = e; }
            int i1 = -1; float v1 = -3.0e38f;
#pragma unroll
            for (int e = 0; e < NEXP; e++) if (e != i0 && acc[e] > v1) { v1 = acc[e]; i1 = e; }
            float ex = __expf(v1 - v0);
            float w0 = 1.f / (1.f + ex);
            float w1 = 1.f - w0;
            int s0 = atomicAdd(&a.counts[i0], 1);
            a.tok[i0 * T_TOK + s0] = t; a.tw[i0 * T_TOK + s0] = w0;
            a.tslot[t * 2] = ((unsigned)i0 << 16) | (unsigned)s0;
            int s1 = atomicAdd(&a.counts[i1], 1);
            a.tok[i1 * T_TOK + s1] = t; a.tw[i1 * T_TOK + s1] = w1;
            a.tslot[t * 2 + 1] = ((unsigned)i1 << 16) | (unsigned)s1;
        }
    }
}

// ============ gate+up GEMM (z<9) + down-weight convert (z==9) ============
// GEMM: 256 threads / 4 waves; block 64Mx128N; wave 64Mx32N; BK=64; XOR-swizzled LDS.
#define EDW_F4 5767168
__global__ __launch_bounds__(256, 3)
void gate_up_bf(const u16* __restrict__ xb,
                const u16* __restrict__ egb, const u16* __restrict__ eub,
                const u16* __restrict__ sgb, const u16* __restrict__ sub,
                const int* __restrict__ counts, const int* __restrict__ tok,
                const float* __restrict__ tw,
                u16* __restrict__ h_r, u16* __restrict__ h_s,
                const float* __restrict__ edw_f, const float* __restrict__ sdw_f,
                u16* __restrict__ edb, u16* __restrict__ sdb) {
    int e = blockIdx.z;
    if (e == 9) {  // convert edw/sdw -> bf16, overlapped with the GEMM blocks
        int b = blockIdx.y * 11 + blockIdx.x;           // 0..175
        size_t base = (size_t)b * 36864 + threadIdx.x;  // 176*36864 = 6488064 f4 exact
        const float4* ein = (const float4*)edw_f;
        const float4* sin_ = (const float4*)sdw_f;
        uint2* eout = (uint2*)edb;
        uint2* sout = (uint2*)sdb;
        for (int it = 0; it < 18; it++) {
            size_t g0 = base + (size_t)it * 2048;
            float4 v[8];
#pragma unroll
            for (int j = 0; j < 8; j++) {
                size_t g = g0 + j * 256;
                v[j] = (g < EDW_F4) ? ein[g] : sin_[g - EDW_F4];
            }
#pragma unroll
            for (int j = 0; j < 8; j++) {
                size_t g = g0 + j * 256;
                if (g < EDW_F4) eout[g] = pack4(v[j]);
                else            sout[g - EDW_F4] = pack4(v[j]);
            }
        }
        return;
    }

    __shared__ u16 lA[64 * 64];    // 8 KB
    __shared__ u16 lG[128 * 64];   // 16 KB
    __shared__ u16 lU[128 * 64];   // 16 KB

    bool routed = (e < NEXP);
    int cnt, hbase; const u16 *Wg, *Wu; u16* hout;
    if (routed) {
        cnt = counts[e];
        int p = 0;
#pragma unroll
        for (int i = 0; i < NEXP; i++) { int c = counts[i]; if (i < e) p += c; }
        hbase = p;
        Wg = egb + (size_t)e * I_DIM * H_DIM;
        Wu = eub + (size_t)e * I_DIM * H_DIM;
        hout = h_r;
    } else { cnt = T_TOK; hbase = 0; Wg = sgb; Wu = sub; hout = h_s; }
    int m0 = blockIdx.y * 64;
    if (m0 >= cnt) return;
    int n0 = blockIdx.x * 128;

    int tid = threadIdx.x, lane = tid & 63, w = tid >> 6;

    // A: 512 chunks (64 rows x 8); wave w instr j<2 covers chunks [w*128+j*64, +64)
    const u16* aptr[2]; u16* alds[2];
#pragma unroll
    for (int j = 0; j < 2; j++) {
        int chunk = w * 128 + j * 64 + lane;
        int row = chunk >> 3, cl = chunk & 7;
        int cg = cl ^ (row & 7);
        int trow = m0 + row; if (trow > cnt - 1) trow = cnt - 1;
        int tix = routed ? tok[e * T_TOK + trow] : trow;
        aptr[j] = xb + (size_t)tix * H_DIM + cg * 8;
        alds[j] = &lA[(w * 128 + j * 64) * 8];
    }
    // G/U: 1024 chunks each; wave w instr j<4 covers [w*256+j*64, +64)
    const u16* gptr[4]; const u16* uptr[4]; u16* glds[4]; u16* ulds[4];
#pragma unroll
    for (int j = 0; j < 4; j++) {
        int chunk = w * 256 + j * 64 + lane;
        int row = chunk >> 3, cl = chunk & 7;
        int cg = cl ^ (row & 7);
        gptr[j] = Wg + (size_t)(n0 + row) * H_DIM + cg * 8;
        uptr[j] = Wu + (size_t)(n0 + row) * H_DIM + cg * 8;
        glds[j] = &lG[(w * 256 + j * 64) * 8];
        ulds[j] = &lU[(w * 256 + j * 64) * 8];
    }

    f32x4 zero = {0.f, 0.f, 0.f, 0.f};
    f32x4 accg[4][2], accu[4][2];
#pragma unroll
    for (int a = 0; a < 4; a++)
#pragma unroll
        for (int b = 0; b < 2; b++) { accg[a][b] = zero; accu[a][b] = zero; }

    int r16 = lane & 15, q = lane >> 4;

    for (int k0 = 0; k0 < H_DIM; k0 += 64) {
#pragma unroll
        for (int j = 0; j < 2; j++) g2l16(aptr[j] + k0, alds[j]);
#pragma unroll
        for (int j = 0; j < 4; j++) { g2l16(gptr[j] + k0, glds[j]); g2l16(uptr[j] + k0, ulds[j]); }
        __syncthreads();
#pragma unroll
        for (int kh = 0; kh < 2; kh++) {
            bf16x8 af[4], gf[2], uf[2];
#pragma unroll
            for (int mi = 0; mi < 4; mi++) {
                int row = mi * 16 + r16;
                int ch = (kh * 4 + q) ^ (row & 7);
                af[mi] = *(const bf16x8*)&lA[row * 64 + ch * 8];
            }
#pragma unroll
            for (int ni = 0; ni < 2; ni++) {
                int row = w * 32 + ni * 16 + r16;
                int ch = (kh * 4 + q) ^ (row & 7);
                gf[ni] = *(const bf16x8*)&lG[row * 64 + ch * 8];
                uf[ni] = *(const bf16x8*)&lU[row * 64 + ch * 8];
            }
#pragma unroll
            for (int mi = 0; mi < 4; mi++)
#pragma unroll
                for (int ni = 0; ni < 2; ni++) {
                    accg[mi][ni] = __builtin_amdgcn_mfma_f32_16x16x32_bf16(af[mi], gf[ni], accg[mi][ni], 0, 0, 0);
                    accu[mi][ni] = __builtin_amdgcn_mfma_f32_16x16x32_bf16(af[mi], uf[ni], accu[mi][ni], 0, 0, 0);
                }
        }
        __syncthreads();
    }

    // epilogue: C/D col=lane&15, row=(lane>>4)*4+reg
#pragma unroll
    for (int mi = 0; mi < 4; mi++) {
#pragma unroll
        for (int r = 0; r < 4; r++) {
            int row = mi * 16 + q * 4 + r;
            int gr = m0 + row;
            if (gr < cnt) {
                float wt = routed ? tw[e * T_TOK + gr] : 1.0f;
                u16* hrow = hout + (size_t)(hbase + gr) * I_DIM + n0 + w * 32;
#pragma unroll
                for (int ni = 0; ni < 2; ni++) {
                    float g = accg[mi][ni][r], u = accu[mi][ni][r];
                    hrow[ni * 16 + r16] = f2bf((g / (1.f + __expf(-g))) * u * wt);
                }
            }
        }
    }
}

// ============ down GEMM: 256 threads, 64Mx128N, wave 64x32, BK=64; fp32 stores to y ============
__global__ __launch_bounds__(256, 3)
void down_bf(const u16* __restrict__ h_r, const u16* __restrict__ h_s,
             const u16* __restrict__ edb, const u16* __restrict__ sdb,
             const int* __restrict__ counts, const int* __restrict__ tok,
             float* __restrict__ y_r, float* __restrict__ y_s) {
    __shared__ u16 lA[64 * 64];    // 8 KB
    __shared__ u16 lB[128 * 64];   // 16 KB

    int e = blockIdx.z;
    bool routed = (e < NEXP);
    int cnt, hbase; const u16* Wd; const u16* hin;
    if (routed) {
        cnt = counts[e];
        int p = 0;
#pragma unroll
        for (int i = 0; i < NEXP; i++) { int c = counts[i]; if (i < e) p += c; }
        hbase = p;
        Wd = edb + (size_t)e * H_DIM * I_DIM;
        hin = h_r;
    } else { cnt = T_TOK; hbase = 0; Wd = sdb; hin = h_s; }
    int m0 = blockIdx.y * 64;
    if (m0 >= cnt) return;
    int n0 = blockIdx.x * 128;

    int tid = threadIdx.x, lane = tid & 63, w = tid >> 6;

    const u16* aptr[2]; u16* alds[2];
#pragma unroll
    for (int j = 0; j < 2; j++) {
        int chunk = w * 128 + j * 64 + lane;
        int row = chunk >> 3, cl = chunk & 7;
        int cg = cl ^ (row & 7);
        int hr = m0 + row; if (hr > cnt - 1) hr = cnt - 1;
        aptr[j] = hin + (size_t)(hbase + hr) * I_DIM + cg * 8;
        alds[j] = &lA[(w * 128 + j * 64) * 8];
    }
    const u16* bptr[4]; u16* blds[4];
#pragma unroll
    for (int j = 0; j < 4; j++) {
        int chunk = w * 256 + j * 64 + lane;
        int row = chunk >> 3, cl = chunk & 7;
        int cg = cl ^ (row & 7);
        bptr[j] = Wd + (size_t)(n0 + row) * I_DIM + cg * 8;
        blds[j] = &lB[(w * 256 + j * 64) * 8];
    }

    f32x4 zero = {0.f, 0.f, 0.f, 0.f};
    f32x4 acc[4][2];
#pragma unroll
    for (int a = 0; a < 4; a++)
#pragma unroll
        for (int b = 0; b < 2; b++) acc[a][b] = zero;

    int r16 = lane & 15, q = lane >> 4;

    for (int k0 = 0; k0 < I_DIM; k0 += 64) {  // 1408 = 22*64
#pragma unroll
        for (int j = 0; j < 2; j++) g2l16(aptr[j] + k0, alds[j]);
#pragma unroll
        for (int j = 0; j < 4; j++) g2l16(bptr[j] + k0, blds[j]);
        __syncthreads();
#pragma unroll
        for (int kh = 0; kh < 2; kh++) {
            bf16x8 af[4], bfr[2];
#pragma unroll
            for (int mi = 0; mi < 4; mi++) {
                int row = mi * 16 + r16;
                int ch = (kh * 4 + q) ^ (row & 7);
                af[mi] = *(const bf16x8*)&lA[row * 64 + ch * 8];
            }
#pragma unroll
            for (int ni = 0; ni < 2; ni++) {
                int row = w * 32 + ni * 16 + r16;
                int ch = (kh * 4 + q) ^ (row & 7);
                bfr[ni] = *(const bf16x8*)&lB[row * 64 + ch * 8];
            }
#pragma unroll
            for (int mi = 0; mi < 4; mi++)
#pragma unroll
                for (int ni = 0; ni < 2; ni++)
                    acc[mi][ni] = __builtin_amdgcn_mfma_f32_16x16x32_bf16(af[mi], bfr[ni], acc[mi][ni], 0, 0, 0);
        }
        __syncthreads();
    }

#pragma unroll
    for (int mi = 0; mi < 4; mi++) {
#pragma unroll
        for (int r = 0; r < 4; r++) {
            int row = mi * 16 + q * 4 + r;
            int gr = m0 + row;
            if (gr < cnt) {
                float* yrow = (routed ? y_r + (size_t)(hbase + gr) * H_DIM
                                      : y_s + (size_t)gr * H_DIM) + n0 + w * 32;
#pragma unroll
                for (int ni = 0; ni < 2; ni++)
                    yrow[ni * 16 + r16] = acc[mi][ni][r];
            }
        }
    }
}

// ============ reduce: out[t] = y_s[t] + y_r[slot0(t)] + y_r[slot1(t)] ============
__global__ __launch_bounds__(256)
void reduce_kernel(const int* __restrict__ counts, const unsigned* __restrict__ tslot,
                   const float* __restrict__ y_r, const float* __restrict__ y_s,
                   float* __restrict__ out) {
    int t = blockIdx.x;
    int pre[NEXP]; int run = 0;
#pragma unroll
    for (int i = 0; i < NEXP; i++) { pre[i] = run; run += counts[i]; }
    unsigned t0 = tslot[t * 2], t1 = tslot[t * 2 + 1];
    int r0 = pre[t0 >> 16] + (int)(t0 & 0xffffu);
    int r1 = pre[t1 >> 16] + (int)(t1 & 0xffffu);
    const float4* ys = (const float4*)(y_s + (size_t)t * H_DIM);
    const float4* a0 = (const float4*)(y_r + (size_t)r0 * H_DIM);
    const float4* a1 = (const float4*)(y_r + (size_t)r1 * H_DIM);
    float4* o = (float4*)(out + (size_t)t * H_DIM);
#pragma unroll
    for (int j = 0; j < 2; j++) {
        int c = threadIdx.x + j * 256;  // 512 float4 per row
        float4 s = ys[c], b0 = a0[c], b1 = a1[c];
        float4 r;
        r.x = s.x + b0.x + b1.x; r.y = s.y + b0.y + b1.y;
        r.z = s.z + b0.z + b1.z; r.w = s.w + b0.w + b1.w;
        o[c] = r;
    }
}

// ================= FALLBACK PATH (fp32, only if ws too small) =================
__global__ __launch_bounds__(256)
void router_kernel(const float* __restrict__ x, const float* __restrict__ gw,
                   int* __restrict__ counts, int* __restrict__ tok, float* __restrict__ tw) {
    int wave = threadIdx.x >> 6;
    int lane = threadIdx.x & 63;
    int t = blockIdx.x * 4 + wave;
    const float* xr = x + (size_t)t * H_DIM;
    float acc[NEXP];
#pragma unroll
    for (int e = 0; e < NEXP; e++) acc[e] = 0.f;
    for (int h = lane; h < H_DIM; h += 64) {
        float xv = xr[h];
#pragma unroll
        for (int e = 0; e < NEXP; e++) acc[e] += xv * gw[e * H_DIM + h];
    }
#pragma unroll
    for (int e = 0; e < NEXP; e++) {
#pragma unroll
        for (int off = 32; off > 0; off >>= 1) acc[e] += __shfl_xor(acc[e], off);
    }
    if (lane == 0) {
        int i0 = 0; float v0 = acc[0];
#pragma unroll
        for (int e = 1; e < NEXP; e++) if (acc[e] > v0) { v0 = acc[e]; i0 = e; }
        int i1 = -1; float v1 = -3.0e38f;
#pragma unroll
        for (int e = 0; e < NEXP; e++) if (e != i0 && acc[e] > v1) { v1 = acc[e]; i1 = e; }
        float ex = __expf(v1 - v0);
        float w0 = 1.f / (1.f + ex);
        float w1 = 1.f - w0;
        int s0 = atomicAdd(&counts[i0], 1);
        tok[i0 * T_TOK + s0] = t; tw[i0 * T_TOK + s0] = w0;
        int s1 = atomicAdd(&counts[i1], 1);
        tok[i1 * T_TOK + s1] = t; tw[i1 * T_TOK + s1] = w1;
    }
}

__global__ __launch_bounds__(256, 2)
void gate_up_f32(const float* __restrict__ x,
                 const float* __restrict__ egw, const float* __restrict__ euw,
                 const float* __restrict__ sgw, const float* __restrict__ suw,
                 const int* __restrict__ counts, const int* __restrict__ tok,
                 const float* __restrict__ tw,
                 u16* __restrict__ h_r, u16* __restrict__ h_s) {
    __shared__ u16 lA[64 * LS];
    __shared__ u16 lG[128 * LS];
    __shared__ u16 lU[128 * LS];
    int e = blockIdx.z;
    bool routed = (e < NEXP);
    int cnt, hbase; const float *Wg, *Wu; u16* hout;
    if (routed) {
        cnt = counts[e];
        int p = 0;
#pragma unroll
        for (int i = 0; i < NEXP; i++) { int c = counts[i]; if (i < e) p += c; }
        hbase = p;
        Wg = egw + (size_t)e * I_DIM * H_DIM; Wu = euw + (size_t)e * I_DIM * H_DIM; hout = h_r;
    } else { cnt = T_TOK; hbase = 0; Wg = sgw; Wu = suw; hout = h_s; }
    int m0 = blockIdx.y * 64;
    if (m0 >= cnt) return;
    int n0 = blockIdx.x * 128;
    int tid = threadIdx.x, lane = tid & 63, w = tid >> 6;
    const float* ap[2]; int sa[2];
#pragma unroll
    for (int i = 0; i < 2; i++) {
        int slot = tid + i * 256;
        int row = slot >> 3, c4 = slot & 7;
        sa[i] = row * LS + c4 * 4;
        int trow = m0 + row; if (trow > cnt - 1) trow = cnt - 1;
        int tix = routed ? tok[e * T_TOK + trow] : trow;
        ap[i] = x + (size_t)tix * H_DIM + c4 * 4;
    }
    const float* gp[4]; const float* up[4]; int sg[4];
#pragma unroll
    for (int i = 0; i < 4; i++) {
        int slot = tid + i * 256;
        int row = slot >> 3, c4 = slot & 7;
        sg[i] = row * LS + c4 * 4;
        gp[i] = Wg + (size_t)(n0 + row) * H_DIM + c4 * 4;
        up[i] = Wu + (size_t)(n0 + row) * H_DIM + c4 * 4;
    }
    f32x4 zero = {0.f, 0.f, 0.f, 0.f};
    f32x4 accg[4][2], accu[4][2];
#pragma unroll
    for (int a = 0; a < 4; a++)
#pragma unroll
        for (int b = 0; b < 2; b++) { accg[a][b] = zero; accu[a][b] = zero; }
    int r16 = lane & 15, kq = lane >> 4;
    float4 ra[2], rg[4], ru[4];
#pragma unroll
    for (int i = 0; i < 2; i++) ra[i] = *(const float4*)(ap[i]);
#pragma unroll
    for (int i = 0; i < 4; i++) { rg[i] = *(const float4*)(gp[i]); ru[i] = *(const float4*)(up[i]); }
    for (int k0 = 0; k0 < H_DIM; k0 += 32) {
#pragma unroll
        for (int i = 0; i < 2; i++) *(uint2*)&lA[sa[i]] = pack4(ra[i]);
#pragma unroll
        for (int i = 0; i < 4; i++) { *(uint2*)&lG[sg[i]] = pack4(rg[i]); *(uint2*)&lU[sg[i]] = pack4(ru[i]); }
        __syncthreads();
        if (k0 + 32 < H_DIM) {
            int kn = k0 + 32;
#pragma unroll
            for (int i = 0; i < 2; i++) ra[i] = *(const float4*)(ap[i] + kn);
#pragma unroll
            for (int i = 0; i < 4; i++) { rg[i] = *(const float4*)(gp[i] + kn); ru[i] = *(const float4*)(up[i] + kn); }
        }
        bf16x8 af[4], gf[2], uf[2];
#pragma unroll
        for (int mi = 0; mi < 4; mi++) af[mi] = *(const bf16x8*)&lA[(mi * 16 + r16) * LS + kq * 8];
#pragma unroll
        for (int ni = 0; ni < 2; ni++) {
            gf[ni] = *(const bf16x8*)&lG[(w * 32 + ni * 16 + r16) * LS + kq * 8];
            uf[ni] = *(const bf16x8*)&lU[(w * 32 + ni * 16 + r16) * LS + kq * 8];
        }
#pragma unroll
        for (int mi = 0; mi < 4; mi++)
#pragma unroll
            for (int ni = 0; ni < 2; ni++) {
                accg[mi][ni] = __builtin_amdgcn_mfma_f32_16x16x32_bf16(af[mi], gf[ni], accg[mi][ni], 0, 0, 0);
                accu[mi][ni] = __builtin_amdgcn_mfma_f32_16x16x32_bf16(af[mi], uf[ni], accu[mi][ni], 0, 0, 0);
            }
        __syncthreads();
    }
#pragma unroll
    for (int mi = 0; mi < 4; mi++) {
#pragma unroll
        for (int r = 0; r < 4; r++) {
            int row = mi * 16 + kq * 4 + r;
            int gr = m0 + row;
            if (gr < cnt) {
                float wt = routed ? tw[e * T_TOK + gr] : 1.0f;
                u16* hrow = hout + (size_t)(hbase + gr) * I_DIM + n0 + w * 32;
#pragma unroll
                for (int ni = 0; ni < 2; ni++) {
                    float g = accg[mi][ni][r], u = accu[mi][ni][r];
                    hrow[ni * 16 + r16] = f2bf((g / (1.f + __expf(-g))) * u * wt);
                }
            }
        }
    }
}

__global__ __launch_bounds__(256, 2)
void down_f32(const u16* __restrict__ h_r, const u16* __restrict__ h_s,
              const float* __restrict__ edw, const float* __restrict__ sdw,
              const int* __restrict__ counts, const int* __restrict__ tok,
              float* __restrict__ out) {
    __shared__ u16 lA[64 * LS];
    __shared__ u16 lB[128 * LS];
    int e = blockIdx.z;
    bool routed = (e < NEXP);
    int cnt, hbase; const float* Wd; const u16* hin;
    if (routed) {
        cnt = counts[e];
        int p = 0;
#pragma unroll
        for (int i = 0; i < NEXP; i++) { int c = counts[i]; if (i < e) p += c; }
        hbase = p;
        Wd = edw + (size_t)e * H_DIM * I_DIM; hin = h_r;
    } else { cnt = T_TOK; hbase = 0; Wd = sdw; hin = h_s; }
    int m0 = blockIdx.y * 64;
    if (m0 >= cnt) return;
    int n0 = blockIdx.x * 128;
    int tid = threadIdx.x, lane = tid & 63, w = tid >> 6;
    int arow = tid >> 2, ac8 = tid & 3;
    int hr = m0 + arow; if (hr > cnt - 1) hr = cnt - 1;
    const u16* ap = hin + (size_t)(hbase + hr) * I_DIM + ac8 * 8;
    int sa = arow * LS + ac8 * 8;
    const float* bp[4]; int sb[4];
#pragma unroll
    for (int i = 0; i < 4; i++) {
        int slot = tid + i * 256;
        int row = slot >> 3, c4 = slot & 7;
        bp[i] = Wd + (size_t)(n0 + row) * I_DIM + c4 * 4;
        sb[i] = row * LS + c4 * 4;
    }
    f32x4 zero = {0.f, 0.f, 0.f, 0.f};
    f32x4 acc[4][2];
#pragma unroll
    for (int a = 0; a < 4; a++)
#pragma unroll
        for (int b = 0; b < 2; b++) acc[a][b] = zero;
    int r16 = lane & 15, kq = lane >> 4;
    uint4 ra = *(const uint4*)(ap);
    float4 rb[4];
#pragma unroll
    for (int i = 0; i < 4; i++) rb[i] = *(const float4*)(bp[i]);
    for (int k0 = 0; k0 < I_DIM; k0 += 32) {
        *(uint4*)&lA[sa] = ra;
#pragma unroll
        for (int i = 0; i < 4; i++) *(uint2*)&lB[sb[i]] = pack4(rb[i]);
        __syncthreads();
        if (k0 + 32 < I_DIM) {
            int kn = k0 + 32;
            ra = *(const uint4*)(ap + kn);
#pragma unroll
            for (int i = 0; i < 4; i++) rb[i] = *(const float4*)(bp[i] + kn);
        }
        bf16x8 af[4], bfr[2];
#pragma unroll
        for (int mi = 0; mi < 4; mi++) af[mi] = *(const bf16x8*)&lA[(mi * 16 + r16) * LS + kq * 8];
#pragma unroll
        for (int ni = 0; ni < 2; ni++) bfr[ni] = *(const bf16x8*)&lB[(w * 32 + ni * 16 + r16) * LS + kq * 8];
#pragma unroll
        for (int mi = 0; mi < 4; mi++)
#pragma unroll
            for (int ni = 0; ni < 2; ni++)
                acc[mi][ni] = __builtin_amdgcn_mfma_f32_16x16x32_bf16(af[mi], bfr[ni], acc[mi][ni], 0, 0, 0);
        __syncthreads();
    }
#pragma unroll
    for (int mi = 0; mi < 4; mi++) {
#pragma unroll
        for (int r = 0; r < 4; r++) {
            int row = mi * 16 + kq * 4 + r;
            int gr = m0 + row;
            if (gr < cnt) {
                int t = routed ? tok[e * T_TOK + gr] : gr;
                float* orow = out + (size_t)t * H_DIM + n0 + w * 32;
#pragma unroll
                for (int ni = 0; ni < 2; ni++)
                    atomicAdd(&orow[ni * 16 + r16], acc[mi][ni][r]);
            }
        }
    }
}

extern "C" void kernel_launch(void* const* d_in, const int* in_sizes, int n_in,
                              void* d_out, int out_size, void* d_ws, size_t ws_size,
                              hipStream_t stream) {
    const float* x   = (const float*)d_in[0];
    const float* gw  = (const float*)d_in[1];
    const float* egw = (const float*)d_in[2];
    const float* euw = (const float*)d_in[3];
    const float* edw = (const float*)d_in[4];
    const float* sgw = (const float*)d_in[5];
    const float* suw = (const float*)d_in[6];
    const float* sdw = (const float*)d_in[7];
    float* out = (float*)d_out;

    char* ws = (char*)d_ws;
    int*      counts = (int*)ws;                  // 32 B
    int*      tok    = (int*)(ws + 256);          // 32 KB
    float*    tw     = (float*)(ws + 33024);      // 32 KB
    unsigned* tslot  = (unsigned*)(ws + 65792);   // 8 KB
    u16*      h_r    = (u16*)(ws + 73984);        // 5767168 B
    u16*      h_s    = (u16*)(ws + 5841152);      // 2883584 B
    u16*      xb     = (u16*)(ws + 8724736);      // 4194304 B
    u16*      egb    = (u16*)(ws + 12919040);     // 46137344 B
    u16*      eub    = (u16*)(ws + 59056384);     // 46137344 B
    u16*      edb    = (u16*)(ws + 105193728);    // 46137344 B
    u16*      sgb    = (u16*)(ws + 151331072);    // 5767168 B
    u16*      sub    = (u16*)(ws + 157098240);    // 5767168 B
    u16*      sdb    = (u16*)(ws + 162865408);    // 5767168 B -> end 168632576
    // y buffers overlay egb/eub (dead after gate_up dispatch)
    float*    y_r    = (float*)(ws + 12919040);   // 16777216 B
    float*    y_s    = (float*)(ws + 29696256);   // 8388608 B

    hipMemsetAsync(counts, 0, 32, stream);

    const size_t NEED = 168632576ull;
    if (ws_size >= NEED) {
        Prep1Args pa;
        pa.src[0] = egw; pa.dst[0] = egb;
        pa.src[1] = euw; pa.dst[1] = eub;
        pa.src[2] = sgw; pa.dst[2] = sgb;
        pa.src[3] = suw; pa.dst[3] = sub;
        pa.x = x; pa.gw = gw; pa.xb = xb;
        pa.counts = counts; pa.tok = tok; pa.tw = tw; pa.tslot = tslot;
        prep1_kernel<<<1840, 256, 0, stream>>>(pa);
        // z 0..7 routed, z==8 shared, z==9 edw/sdw bf16 convert (overlapped)
        gate_up_bf<<<dim3(11, 16, 10), 256, 0, stream>>>(xb, egb, eub, sgb, sub, counts, tok, tw,
                                                         h_r, h_s, edw, sdw, edb, sdb);
        down_bf<<<dim3(16, 16, 9), 256, 0, stream>>>(h_r, h_s, edb, sdb, counts, tok, y_r, y_s);
        reduce_kernel<<<1024, 256, 0, stream>>>(counts, tslot, y_r, y_s, out);
    } else {
        hipMemsetAsync(out, 0, (size_t)T_TOK * H_DIM * sizeof(float), stream);
        router_kernel<<<256, 256, 0, stream>>>(x, gw, counts, tok, tw);
        gate_up_f32<<<dim3(11, 16, 9), 256, 0, stream>>>(x, egw, euw, sgw, suw, counts, tok, tw, h_r, h_s);
        down_f32<<<dim3(16, 16, 9), 256, 0, stream>>>(h_r, h_s, edw, sdw, counts, tok, out);
    }
}

// Round 2
// 475.897 us; speedup vs baseline: 1.0041x; 1.0041x over previous
//
#include <hip/hip_runtime.h>
#include <hip/hip_bf16.h>

typedef unsigned short u16;
typedef __bf16 bf16x8 __attribute__((ext_vector_type(8)));
typedef float f32x4 __attribute__((ext_vector_type(4)));

#define H_DIM 2048
#define I_DIM 1408
#define T_TOK 1024
#define NEXP 8
#define LS 40  // fallback-path LDS stride

__device__ __forceinline__ u16 f2bf(float f) {
    union { float f; unsigned u; } v; v.f = f;
    unsigned r = v.u + 0x7FFFu + ((v.u >> 16) & 1u);  // RNE
    return (u16)(r >> 16);
}
__device__ __forceinline__ unsigned pack2(float a, float b) {
    float2 t; t.x = a; t.y = b;
    __hip_bfloat162 h = __float22bfloat162_rn(t);  // v_cvt_pk_bf16_f32
    union { __hip_bfloat162 h; unsigned u; } v; v.h = h;
    return v.u;
}
__device__ __forceinline__ uint2 pack4(float4 f) {
    uint2 r; r.x = pack2(f.x, f.y); r.y = pack2(f.z, f.w); return r;
}
__device__ __forceinline__ void g2l16(const void* g, void* l) {
    __builtin_amdgcn_global_load_lds((const __attribute__((address_space(1))) void*)g,
                                     (__attribute__((address_space(3))) void*)l, 16, 0, 0);
}

// ============ prep1: convert gate/up weights (lane-contiguous) + router/x-convert ============
// blocks 0..1583: weight convert (egw 704, euw 704, sgw 88, suw 88; 8192 float4 per block)
// blocks 1584..1839: router (4 tokens/block)
struct Prep1Args {
    const float* src[4]; u16* dst[4];
    const float* x; const float* gw; u16* xb;
    int* counts; int* tok; float* tw; unsigned* tslot;
};

__global__ __launch_bounds__(256)
void prep1_kernel(Prep1Args a) {
    int b = blockIdx.x;
    if (b < 1584) {
        int r, rb;
        if (b < 704)       { r = 0; rb = b; }
        else if (b < 1408) { r = 1; rb = b - 704; }
        else if (b < 1496) { r = 2; rb = b - 1408; }
        else               { r = 3; rb = b - 1496; }
        const float4* in = (const float4*)a.src[r];
        uint2* out = (uint2*)a.dst[r];
        size_t base = (size_t)rb * 8192 + threadIdx.x;
#pragma unroll
        for (int it = 0; it < 4; it++) {
            float4 v[8];
#pragma unroll
            for (int j = 0; j < 8; j++) v[j] = in[base + it * 2048 + j * 256];
#pragma unroll
            for (int j = 0; j < 8; j++) out[base + it * 2048 + j * 256] = pack4(v[j]);
        }
    } else {
        int wave = threadIdx.x >> 6, lane = threadIdx.x & 63;
        int t = (b - 1584) * 4 + wave;
        const float4* xr = (const float4*)(a.x + (size_t)t * H_DIM);
        const float4* gw4 = (const float4*)a.gw;
        uint2* xbr = (uint2*)(a.xb + (size_t)t * H_DIM);
        float acc[NEXP];
#pragma unroll
        for (int e = 0; e < NEXP; e++) acc[e] = 0.f;
#pragma unroll
        for (int j = 0; j < 8; j++) {
            int c = lane + j * 64;
            float4 xv = xr[c];
            xbr[c] = pack4(xv);
#pragma unroll
            for (int e = 0; e < NEXP; e++) {
                float4 gv = gw4[e * 512 + c];
                acc[e] += xv.x * gv.x + xv.y * gv.y + xv.z * gv.z + xv.w * gv.w;
            }
        }
#pragma unroll
        for (int e = 0; e < NEXP; e++) {
#pragma unroll
            for (int off = 32; off > 0; off >>= 1) acc[e] += __shfl_xor(acc[e], off);
        }
        if (lane == 0) {
            int i0 = 0; float v0 = acc[0];
#pragma unroll
            for (int e = 1; e < NEXP; e++) if (acc[e] > v0) { v0 = acc[e]; i0 = e; }
            int i1 = -1; float v1 = -3.0e38f;
#pragma unroll
            for (int e = 0; e < NEXP; e++) if (e != i0 && acc[e] > v1) { v1 = acc[e]; i1 = e; }
            float ex = __expf(v1 - v0);
            float w0 = 1.f / (1.f + ex);
            float w1 = 1.f - w0;
            int s0 = atomicAdd(&a.counts[i0], 1);
            a.tok[i0 * T_TOK + s0] = t; a.tw[i0 * T_TOK + s0] = w0;
            a.tslot[t * 2] = ((unsigned)i0 << 16) | (unsigned)s0;
            int s1 = atomicAdd(&a.counts[i1], 1);
            a.tok[i1 * T_TOK + s1] = t; a.tw[i1 * T_TOK + s1] = w1;
            a.tslot[t * 2 + 1] = ((unsigned)i1 << 16) | (unsigned)s1;
        }
    }
}

// ============ gate+up GEMM (z<9) + down-weight convert (z==9) ============
// GEMM: 256 threads / 4 waves; block 64Mx128N; wave 64Mx32N; BK=64; XOR-swizzled LDS.
// Double-buffered LDS: issue next K-tile's global_load_lds BEFORE computing current tile,
// so the barrier's vmcnt(0) drain overlaps with the MFMA phase (T3-minimum pipeline).
#define EDW_F4 5767168
__global__ __launch_bounds__(256, 2)
void gate_up_bf(const u16* __restrict__ xb,
                const u16* __restrict__ egb, const u16* __restrict__ eub,
                const u16* __restrict__ sgb, const u16* __restrict__ sub,
                const int* __restrict__ counts, const int* __restrict__ tok,
                const float* __restrict__ tw,
                u16* __restrict__ h_r, u16* __restrict__ h_s,
                const float* __restrict__ edw_f, const float* __restrict__ sdw_f,
                u16* __restrict__ edb, u16* __restrict__ sdb) {
    int e = blockIdx.z;
    if (e == 9) {  // convert edw/sdw -> bf16, overlapped with the GEMM blocks
        int b = blockIdx.y * 11 + blockIdx.x;           // 0..175
        size_t base = (size_t)b * 36864 + threadIdx.x;  // 176*36864 = 6488064 f4 exact
        const float4* ein = (const float4*)edw_f;
        const float4* sin_ = (const float4*)sdw_f;
        uint2* eout = (uint2*)edb;
        uint2* sout = (uint2*)sdb;
        for (int it = 0; it < 18; it++) {
            size_t g0 = base + (size_t)it * 2048;
            float4 v[8];
#pragma unroll
            for (int j = 0; j < 8; j++) {
                size_t g = g0 + j * 256;
                v[j] = (g < EDW_F4) ? ein[g] : sin_[g - EDW_F4];
            }
#pragma unroll
            for (int j = 0; j < 8; j++) {
                size_t g = g0 + j * 256;
                if (g < EDW_F4) eout[g] = pack4(v[j]);
                else            sout[g - EDW_F4] = pack4(v[j]);
            }
        }
        return;
    }

    __shared__ u16 lA[2][64 * 64];    // 2 x 8 KB
    __shared__ u16 lG[2][128 * 64];   // 2 x 16 KB
    __shared__ u16 lU[2][128 * 64];   // 2 x 16 KB  -> 80 KB total

    bool routed = (e < NEXP);
    int cnt, hbase; const u16 *Wg, *Wu; u16* hout;
    if (routed) {
        cnt = counts[e];
        int p = 0;
#pragma unroll
        for (int i = 0; i < NEXP; i++) { int c = counts[i]; if (i < e) p += c; }
        hbase = p;
        Wg = egb + (size_t)e * I_DIM * H_DIM;
        Wu = eub + (size_t)e * I_DIM * H_DIM;
        hout = h_r;
    } else { cnt = T_TOK; hbase = 0; Wg = sgb; Wu = sub; hout = h_s; }
    int m0 = blockIdx.y * 64;
    if (m0 >= cnt) return;
    int n0 = blockIdx.x * 128;

    int tid = threadIdx.x, lane = tid & 63, w = tid >> 6;

    // A: 512 chunks (64 rows x 8); wave w instr j<2 covers chunks [w*128+j*64, +64)
    const u16* aptr[2]; int aoff[2];
#pragma unroll
    for (int j = 0; j < 2; j++) {
        int chunk = w * 128 + j * 64 + lane;
        int row = chunk >> 3, cl = chunk & 7;
        int cg = cl ^ (row & 7);
        int trow = m0 + row; if (trow > cnt - 1) trow = cnt - 1;
        int tix = routed ? tok[e * T_TOK + trow] : trow;
        aptr[j] = xb + (size_t)tix * H_DIM + cg * 8;
        aoff[j] = (w * 128 + j * 64) * 8;
    }
    // G/U: 1024 chunks each; wave w instr j<4 covers [w*256+j*64, +64)
    const u16* gptr[4]; const u16* uptr[4]; int goff[4];
#pragma unroll
    for (int j = 0; j < 4; j++) {
        int chunk = w * 256 + j * 64 + lane;
        int row = chunk >> 3, cl = chunk & 7;
        int cg = cl ^ (row & 7);
        gptr[j] = Wg + (size_t)(n0 + row) * H_DIM + cg * 8;
        uptr[j] = Wu + (size_t)(n0 + row) * H_DIM + cg * 8;
        goff[j] = (w * 256 + j * 64) * 8;
    }

    f32x4 zero = {0.f, 0.f, 0.f, 0.f};
    f32x4 accg[4][2], accu[4][2];
#pragma unroll
    for (int a = 0; a < 4; a++)
#pragma unroll
        for (int b = 0; b < 2; b++) { accg[a][b] = zero; accu[a][b] = zero; }

    int r16 = lane & 15, q = lane >> 4;

    auto stage = [&](int B, int K0) {
#pragma unroll
        for (int j = 0; j < 2; j++) g2l16(aptr[j] + K0, &lA[B][aoff[j]]);
#pragma unroll
        for (int j = 0; j < 4; j++) {
            g2l16(gptr[j] + K0, &lG[B][goff[j]]);
            g2l16(uptr[j] + K0, &lU[B][goff[j]]);
        }
    };
    auto compute = [&](const u16* A_, const u16* G_, const u16* U_) {
#pragma unroll
        for (int kh = 0; kh < 2; kh++) {
            bf16x8 af[4], gf[2], uf[2];
#pragma unroll
            for (int mi = 0; mi < 4; mi++) {
                int row = mi * 16 + r16;
                int ch = (kh * 4 + q) ^ (row & 7);
                af[mi] = *(const bf16x8*)&A_[row * 64 + ch * 8];
            }
#pragma unroll
            for (int ni = 0; ni < 2; ni++) {
                int row = w * 32 + ni * 16 + r16;
                int ch = (kh * 4 + q) ^ (row & 7);
                gf[ni] = *(const bf16x8*)&G_[row * 64 + ch * 8];
                uf[ni] = *(const bf16x8*)&U_[row * 64 + ch * 8];
            }
#pragma unroll
            for (int mi = 0; mi < 4; mi++)
#pragma unroll
                for (int ni = 0; ni < 2; ni++) {
                    accg[mi][ni] = __builtin_amdgcn_mfma_f32_16x16x32_bf16(af[mi], gf[ni], accg[mi][ni], 0, 0, 0);
                    accu[mi][ni] = __builtin_amdgcn_mfma_f32_16x16x32_bf16(af[mi], uf[ni], accu[mi][ni], 0, 0, 0);
                }
        }
    };

    // H_DIM = 2048 = 16 * 128 -> clean buf0/buf1 pairs
    stage(0, 0);
    __syncthreads();
    for (int k0 = 0; k0 < H_DIM; k0 += 128) {
        stage(1, k0 + 64);            // prefetch into buf1, in flight during compute(buf0)
        compute(lA[0], lG[0], lU[0]);
        __syncthreads();              // drains vmcnt -> buf1 ready; all waves done reading buf0
        if (k0 + 128 < H_DIM) stage(0, k0 + 128);
        compute(lA[1], lG[1], lU[1]);
        __syncthreads();
    }

    // epilogue: C/D col=lane&15, row=(lane>>4)*4+reg
#pragma unroll
    for (int mi = 0; mi < 4; mi++) {
#pragma unroll
        for (int r = 0; r < 4; r++) {
            int row = mi * 16 + q * 4 + r;
            int gr = m0 + row;
            if (gr < cnt) {
                float wt = routed ? tw[e * T_TOK + gr] : 1.0f;
                u16* hrow = hout + (size_t)(hbase + gr) * I_DIM + n0 + w * 32;
#pragma unroll
                for (int ni = 0; ni < 2; ni++) {
                    float g = accg[mi][ni][r], u = accu[mi][ni][r];
                    hrow[ni * 16 + r16] = f2bf((g / (1.f + __expf(-g))) * u * wt);
                }
            }
        }
    }
}

// ============ down GEMM: 256 threads, 64Mx128N, wave 64x32, BK=64; fp32 stores to y ============
// Same depth-1 double-buffered pipeline as gate_up_bf.
__global__ __launch_bounds__(256, 3)
void down_bf(const u16* __restrict__ h_r, const u16* __restrict__ h_s,
             const u16* __restrict__ edb, const u16* __restrict__ sdb,
             const int* __restrict__ counts, const int* __restrict__ tok,
             float* __restrict__ y_r, float* __restrict__ y_s) {
    __shared__ u16 lA[2][64 * 64];    // 2 x 8 KB
    __shared__ u16 lB[2][128 * 64];   // 2 x 16 KB -> 48 KB total

    int e = blockIdx.z;
    bool routed = (e < NEXP);
    int cnt, hbase; const u16* Wd; const u16* hin;
    if (routed) {
        cnt = counts[e];
        int p = 0;
#pragma unroll
        for (int i = 0; i < NEXP; i++) { int c = counts[i]; if (i < e) p += c; }
        hbase = p;
        Wd = edb + (size_t)e * H_DIM * I_DIM;
        hin = h_r;
    } else { cnt = T_TOK; hbase = 0; Wd = sdb; hin = h_s; }
    int m0 = blockIdx.y * 64;
    if (m0 >= cnt) return;
    int n0 = blockIdx.x * 128;

    int tid = threadIdx.x, lane = tid & 63, w = tid >> 6;

    const u16* aptr[2]; int aoff[2];
#pragma unroll
    for (int j = 0; j < 2; j++) {
        int chunk = w * 128 + j * 64 + lane;
        int row = chunk >> 3, cl = chunk & 7;
        int cg = cl ^ (row & 7);
        int hr = m0 + row; if (hr > cnt - 1) hr = cnt - 1;
        aptr[j] = hin + (size_t)(hbase + hr) * I_DIM + cg * 8;
        aoff[j] = (w * 128 + j * 64) * 8;
    }
    const u16* bptr[4]; int boff[4];
#pragma unroll
    for (int j = 0; j < 4; j++) {
        int chunk = w * 256 + j * 64 + lane;
        int row = chunk >> 3, cl = chunk & 7;
        int cg = cl ^ (row & 7);
        bptr[j] = Wd + (size_t)(n0 + row) * I_DIM + cg * 8;
        boff[j] = (w * 256 + j * 64) * 8;
    }

    f32x4 zero = {0.f, 0.f, 0.f, 0.f};
    f32x4 acc[4][2];
#pragma unroll
    for (int a = 0; a < 4; a++)
#pragma unroll
        for (int b = 0; b < 2; b++) acc[a][b] = zero;

    int r16 = lane & 15, q = lane >> 4;

    auto stage = [&](int B, int K0) {
#pragma unroll
        for (int j = 0; j < 2; j++) g2l16(aptr[j] + K0, &lA[B][aoff[j]]);
#pragma unroll
        for (int j = 0; j < 4; j++) g2l16(bptr[j] + K0, &lB[B][boff[j]]);
    };
    auto compute = [&](const u16* A_, const u16* B_) {
#pragma unroll
        for (int kh = 0; kh < 2; kh++) {
            bf16x8 af[4], bfr[2];
#pragma unroll
            for (int mi = 0; mi < 4; mi++) {
                int row = mi * 16 + r16;
                int ch = (kh * 4 + q) ^ (row & 7);
                af[mi] = *(const bf16x8*)&A_[row * 64 + ch * 8];
            }
#pragma unroll
            for (int ni = 0; ni < 2; ni++) {
                int row = w * 32 + ni * 16 + r16;
                int ch = (kh * 4 + q) ^ (row & 7);
                bfr[ni] = *(const bf16x8*)&B_[row * 64 + ch * 8];
            }
#pragma unroll
            for (int mi = 0; mi < 4; mi++)
#pragma unroll
                for (int ni = 0; ni < 2; ni++)
                    acc[mi][ni] = __builtin_amdgcn_mfma_f32_16x16x32_bf16(af[mi], bfr[ni], acc[mi][ni], 0, 0, 0);
        }
    };

    // I_DIM = 1408 = 11 * 128 -> clean buf0/buf1 pairs
    stage(0, 0);
    __syncthreads();
    for (int k0 = 0; k0 < I_DIM; k0 += 128) {
        stage(1, k0 + 64);
        compute(lA[0], lB[0]);
        __syncthreads();
        if (k0 + 128 < I_DIM) stage(0, k0 + 128);
        compute(lA[1], lB[1]);
        __syncthreads();
    }

#pragma unroll
    for (int mi = 0; mi < 4; mi++) {
#pragma unroll
        for (int r = 0; r < 4; r++) {
            int row = mi * 16 + q * 4 + r;
            int gr = m0 + row;
            if (gr < cnt) {
                float* yrow = (routed ? y_r + (size_t)(hbase + gr) * H_DIM
                                      : y_s + (size_t)gr * H_DIM) + n0 + w * 32;
#pragma unroll
                for (int ni = 0; ni < 2; ni++)
                    yrow[ni * 16 + r16] = acc[mi][ni][r];
            }
        }
    }
}

// ============ reduce: out[t] = y_s[t] + y_r[slot0(t)] + y_r[slot1(t)] ============
__global__ __launch_bounds__(256)
void reduce_kernel(const int* __restrict__ counts, const unsigned* __restrict__ tslot,
                   const float* __restrict__ y_r, const float* __restrict__ y_s,
                   float* __restrict__ out) {
    int t = blockIdx.x;
    int pre[NEXP]; int run = 0;
#pragma unroll
    for (int i = 0; i < NEXP; i++) { pre[i] = run; run += counts[i]; }
    unsigned t0 = tslot[t * 2], t1 = tslot[t * 2 + 1];
    int r0 = pre[t0 >> 16] + (int)(t0 & 0xffffu);
    int r1 = pre[t1 >> 16] + (int)(t1 & 0xffffu);
    const float4* ys = (const float4*)(y_s + (size_t)t * H_DIM);
    const float4* a0 = (const float4*)(y_r + (size_t)r0 * H_DIM);
    const float4* a1 = (const float4*)(y_r + (size_t)r1 * H_DIM);
    float4* o = (float4*)(out + (size_t)t * H_DIM);
#pragma unroll
    for (int j = 0; j < 2; j++) {
        int c = threadIdx.x + j * 256;  // 512 float4 per row
        float4 s = ys[c], b0 = a0[c], b1 = a1[c];
        float4 r;
        r.x = s.x + b0.x + b1.x; r.y = s.y + b0.y + b1.y;
        r.z = s.z + b0.z + b1.z; r.w = s.w + b0.w + b1.w;
        o[c] = r;
    }
}

// ================= FALLBACK PATH (fp32, only if ws too small) =================
__global__ __launch_bounds__(256)
void router_kernel(const float* __restrict__ x, const float* __restrict__ gw,
                   int* __restrict__ counts, int* __restrict__ tok, float* __restrict__ tw) {
    int wave = threadIdx.x >> 6;
    int lane = threadIdx.x & 63;
    int t = blockIdx.x * 4 + wave;
    const float* xr = x + (size_t)t * H_DIM;
    float acc[NEXP];
#pragma unroll
    for (int e = 0; e < NEXP; e++) acc[e] = 0.f;
    for (int h = lane; h < H_DIM; h += 64) {
        float xv = xr[h];
#pragma unroll
        for (int e = 0; e < NEXP; e++) acc[e] += xv * gw[e * H_DIM + h];
    }
#pragma unroll
    for (int e = 0; e < NEXP; e++) {
#pragma unroll
        for (int off = 32; off > 0; off >>= 1) acc[e] += __shfl_xor(acc[e], off);
    }
    if (lane == 0) {
        int i0 = 0; float v0 = acc[0];
#pragma unroll
        for (int e = 1; e < NEXP; e++) if (acc[e] > v0) { v0 = acc[e]; i0 = e; }
        int i1 = -1; float v1 = -3.0e38f;
#pragma unroll
        for (int e = 0; e < NEXP; e++) if (e != i0 && acc[e] > v1) { v1 = acc[e]; i1 = e; }
        float ex = __expf(v1 - v0);
        float w0 = 1.f / (1.f + ex);
        float w1 = 1.f - w0;
        int s0 = atomicAdd(&counts[i0], 1);
        tok[i0 * T_TOK + s0] = t; tw[i0 * T_TOK + s0] = w0;
        int s1 = atomicAdd(&counts[i1], 1);
        tok[i1 * T_TOK + s1] = t; tw[i1 * T_TOK + s1] = w1;
    }
}

__global__ __launch_bounds__(256, 2)
void gate_up_f32(const float* __restrict__ x,
                 const float* __restrict__ egw, const float* __restrict__ euw,
                 const float* __restrict__ sgw, const float* __restrict__ suw,
                 const int* __restrict__ counts, const int* __restrict__ tok,
                 const float* __restrict__ tw,
                 u16* __restrict__ h_r, u16* __restrict__ h_s) {
    __shared__ u16 lA[64 * LS];
    __shared__ u16 lG[128 * LS];
    __shared__ u16 lU[128 * LS];
    int e = blockIdx.z;
    bool routed = (e < NEXP);
    int cnt, hbase; const float *Wg, *Wu; u16* hout;
    if (routed) {
        cnt = counts[e];
        int p = 0;
#pragma unroll
        for (int i = 0; i < NEXP; i++) { int c = counts[i]; if (i < e) p += c; }
        hbase = p;
        Wg = egw + (size_t)e * I_DIM * H_DIM; Wu = euw + (size_t)e * I_DIM * H_DIM; hout = h_r;
    } else { cnt = T_TOK; hbase = 0; Wg = sgw; Wu = suw; hout = h_s; }
    int m0 = blockIdx.y * 64;
    if (m0 >= cnt) return;
    int n0 = blockIdx.x * 128;
    int tid = threadIdx.x, lane = tid & 63, w = tid >> 6;
    const float* ap[2]; int sa[2];
#pragma unroll
    for (int i = 0; i < 2; i++) {
        int slot = tid + i * 256;
        int row = slot >> 3, c4 = slot & 7;
        sa[i] = row * LS + c4 * 4;
        int trow = m0 + row; if (trow > cnt - 1) trow = cnt - 1;
        int tix = routed ? tok[e * T_TOK + trow] : trow;
        ap[i] = x + (size_t)tix * H_DIM + c4 * 4;
    }
    const float* gp[4]; const float* up[4]; int sg[4];
#pragma unroll
    for (int i = 0; i < 4; i++) {
        int slot = tid + i * 256;
        int row = slot >> 3, c4 = slot & 7;
        sg[i] = row * LS + c4 * 4;
        gp[i] = Wg + (size_t)(n0 + row) * H_DIM + c4 * 4;
        up[i] = Wu + (size_t)(n0 + row) * H_DIM + c4 * 4;
    }
    f32x4 zero = {0.f, 0.f, 0.f, 0.f};
    f32x4 accg[4][2], accu[4][2];
#pragma unroll
    for (int a = 0; a < 4; a++)
#pragma unroll
        for (int b = 0; b < 2; b++) { accg[a][b] = zero; accu[a][b] = zero; }
    int r16 = lane & 15, kq = lane >> 4;
    float4 ra[2], rg[4], ru[4];
#pragma unroll
    for (int i = 0; i < 2; i++) ra[i] = *(const float4*)(ap[i]);
#pragma unroll
    for (int i = 0; i < 4; i++) { rg[i] = *(const float4*)(gp[i]); ru[i] = *(const float4*)(up[i]); }
    for (int k0 = 0; k0 < H_DIM; k0 += 32) {
#pragma unroll
        for (int i = 0; i < 2; i++) *(uint2*)&lA[sa[i]] = pack4(ra[i]);
#pragma unroll
        for (int i = 0; i < 4; i++) { *(uint2*)&lG[sg[i]] = pack4(rg[i]); *(uint2*)&lU[sg[i]] = pack4(ru[i]); }
        __syncthreads();
        if (k0 + 32 < H_DIM) {
            int kn = k0 + 32;
#pragma unroll
            for (int i = 0; i < 2; i++) ra[i] = *(const float4*)(ap[i] + kn);
#pragma unroll
            for (int i = 0; i < 4; i++) { rg[i] = *(const float4*)(gp[i] + kn); ru[i] = *(const float4*)(up[i] + kn); }
        }
        bf16x8 af[4], gf[2], uf[2];
#pragma unroll
        for (int mi = 0; mi < 4; mi++) af[mi] = *(const bf16x8*)&lA[(mi * 16 + r16) * LS + kq * 8];
#pragma unroll
        for (int ni = 0; ni < 2; ni++) {
            gf[ni] = *(const bf16x8*)&lG[(w * 32 + ni * 16 + r16) * LS + kq * 8];
            uf[ni] = *(const bf16x8*)&lU[(w * 32 + ni * 16 + r16) * LS + kq * 8];
        }
#pragma unroll
        for (int mi = 0; mi < 4; mi++)
#pragma unroll
            for (int ni = 0; ni < 2; ni++) {
                accg[mi][ni] = __builtin_amdgcn_mfma_f32_16x16x32_bf16(af[mi], gf[ni], accg[mi][ni], 0, 0, 0);
                accu[mi][ni] = __builtin_amdgcn_mfma_f32_16x16x32_bf16(af[mi], uf[ni], accu[mi][ni], 0, 0, 0);
            }
        __syncthreads();
    }
#pragma unroll
    for (int mi = 0; mi < 4; mi++) {
#pragma unroll
        for (int r = 0; r < 4; r++) {
            int row = mi * 16 + kq * 4 + r;
            int gr = m0 + row;
            if (gr < cnt) {
                float wt = routed ? tw[e * T_TOK + gr] : 1.0f;
                u16* hrow = hout + (size_t)(hbase + gr) * I_DIM + n0 + w * 32;
#pragma unroll
                for (int ni = 0; ni < 2; ni++) {
                    float g = accg[mi][ni][r], u = accu[mi][ni][r];
                    hrow[ni * 16 + r16] = f2bf((g / (1.f + __expf(-g))) * u * wt);
                }
            }
        }
    }
}

__global__ __launch_bounds__(256, 2)
void down_f32(const u16* __restrict__ h_r, const u16* __restrict__ h_s,
              const float* __restrict__ edw, const float* __restrict__ sdw,
              const int* __restrict__ counts, const int* __restrict__ tok,
              float* __restrict__ out) {
    __shared__ u16 lA[64 * LS];
    __shared__ u16 lB[128 * LS];
    int e = blockIdx.z;
    bool routed = (e < NEXP);
    int cnt, hbase; const float* Wd; const u16* hin;
    if (routed) {
        cnt = counts[e];
        int p = 0;
#pragma unroll
        for (int i = 0; i < NEXP; i++) { int c = counts[i]; if (i < e) p += c; }
        hbase = p;
        Wd = edw + (size_t)e * H_DIM * I_DIM; hin = h_r;
    } else { cnt = T_TOK; hbase = 0; Wd = sdw; hin = h_s; }
    int m0 = blockIdx.y * 64;
    if (m0 >= cnt) return;
    int n0 = blockIdx.x * 128;
    int tid = threadIdx.x, lane = tid & 63, w = tid >> 6;
    int arow = tid >> 2, ac8 = tid & 3;
    int hr = m0 + arow; if (hr > cnt - 1) hr = cnt - 1;
    const u16* ap = hin + (size_t)(hbase + hr) * I_DIM + ac8 * 8;
    int sa = arow * LS + ac8 * 8;
    const float* bp[4]; int sb[4];
#pragma unroll
    for (int i = 0; i < 4; i++) {
        int slot = tid + i * 256;
        int row = slot >> 3, c4 = slot & 7;
        bp[i] = Wd + (size_t)(n0 + row) * I_DIM + c4 * 4;
        sb[i] = row * LS + c4 * 4;
    }
    f32x4 zero = {0.f, 0.f, 0.f, 0.f};
    f32x4 acc[4][2];
#pragma unroll
    for (int a = 0; a < 4; a++)
#pragma unroll
        for (int b = 0; b < 2; b++) acc[a][b] = zero;
    int r16 = lane & 15, kq = lane >> 4;
    uint4 ra = *(const uint4*)(ap);
    float4 rb[4];
#pragma unroll
    for (int i = 0; i < 4; i++) rb[i] = *(const float4*)(bp[i]);
    for (int k0 = 0; k0 < I_DIM; k0 += 32) {
        *(uint4*)&lA[sa] = ra;
#pragma unroll
        for (int i = 0; i < 4; i++) *(uint2*)&lB[sb[i]] = pack4(rb[i]);
        __syncthreads();
        if (k0 + 32 < I_DIM) {
            int kn = k0 + 32;
            ra = *(const uint4*)(ap + kn);
#pragma unroll
            for (int i = 0; i < 4; i++) rb[i] = *(const float4*)(bp[i] + kn);
        }
        bf16x8 af[4], bfr[2];
#pragma unroll
        for (int mi = 0; mi < 4; mi++) af[mi] = *(const bf16x8*)&lA[(mi * 16 + r16) * LS + kq * 8];
#pragma unroll
        for (int ni = 0; ni < 2; ni++) bfr[ni] = *(const bf16x8*)&lB[(w * 32 + ni * 16 + r16) * LS + kq * 8];
#pragma unroll
        for (int mi = 0; mi < 4; mi++)
#pragma unroll
            for (int ni = 0; ni < 2; ni++)
                acc[mi][ni] = __builtin_amdgcn_mfma_f32_16x16x32_bf16(af[mi], bfr[ni], acc[mi][ni], 0, 0, 0);
        __syncthreads();
    }
#pragma unroll
    for (int mi = 0; mi < 4; mi++) {
#pragma unroll
        for (int r = 0; r < 4; r++) {
            int row = mi * 16 + kq * 4 + r;
            int gr = m0 + row;
            if (gr < cnt) {
                int t = routed ? tok[e * T_TOK + gr] : gr;
                float* orow = out + (size_t)t * H_DIM + n0 + w * 32;
#pragma unroll
                for (int ni = 0; ni < 2; ni++)
                    atomicAdd(&orow[ni * 16 + r16], acc[mi][ni][r]);
            }
        }
    }
}

extern "C" void kernel_launch(void* const* d_in, const int* in_sizes, int n_in,
                              void* d_out, int out_size, void* d_ws, size_t ws_size,
                              hipStream_t stream) {
    const float* x   = (const float*)d_in[0];
    const float* gw  = (const float*)d_in[1];
    const float* egw = (const float*)d_in[2];
    const float* euw = (const float*)d_in[3];
    const float* edw = (const float*)d_in[4];
    const float* sgw = (const float*)d_in[5];
    const float* suw = (const float*)d_in[6];
    const float* sdw = (const float*)d_in[7];
    float* out = (float*)d_out;

    char* ws = (char*)d_ws;
    int*      counts = (int*)ws;                  // 32 B
    int*      tok    = (int*)(ws + 256);          // 32 KB
    float*    tw     = (float*)(ws + 33024);      // 32 KB
    unsigned* tslot  = (unsigned*)(ws + 65792);   // 8 KB
    u16*      h_r    = (u16*)(ws + 73984);        // 5767168 B
    u16*      h_s    = (u16*)(ws + 5841152);      // 2883584 B
    u16*      xb     = (u16*)(ws + 8724736);      // 4194304 B
    u16*      egb    = (u16*)(ws + 12919040);     // 46137344 B
    u16*      eub    = (u16*)(ws + 59056384);     // 46137344 B
    u16*      edb    = (u16*)(ws + 105193728);    // 46137344 B
    u16*      sgb    = (u16*)(ws + 151331072);    // 5767168 B
    u16*      sub    = (u16*)(ws + 157098240);    // 5767168 B
    u16*      sdb    = (u16*)(ws + 162865408);    // 5767168 B -> end 168632576
    // y buffers overlay egb/eub (dead after gate_up dispatch)
    float*    y_r    = (float*)(ws + 12919040);   // 16777216 B
    float*    y_s    = (float*)(ws + 29696256);   // 8388608 B

    hipMemsetAsync(counts, 0, 32, stream);

    const size_t NEED = 168632576ull;
    if (ws_size >= NEED) {
        Prep1Args pa;
        pa.src[0] = egw; pa.dst[0] = egb;
        pa.src[1] = euw; pa.dst[1] = eub;
        pa.src[2] = sgw; pa.dst[2] = sgb;
        pa.src[3] = suw; pa.dst[3] = sub;
        pa.x = x; pa.gw = gw; pa.xb = xb;
        pa.counts = counts; pa.tok = tok; pa.tw = tw; pa.tslot = tslot;
        prep1_kernel<<<1840, 256, 0, stream>>>(pa);
        // z 0..7 routed, z==8 shared, z==9 edw/sdw bf16 convert (overlapped)
        gate_up_bf<<<dim3(11, 16, 10), 256, 0, stream>>>(xb, egb, eub, sgb, sub, counts, tok, tw,
                                                         h_r, h_s, edw, sdw, edb, sdb);
        down_bf<<<dim3(16, 16, 9), 256, 0, stream>>>(h_r, h_s, edb, sdb, counts, tok, y_r, y_s);
        reduce_kernel<<<1024, 256, 0, stream>>>(counts, tslot, y_r, y_s, out);
    } else {
        hipMemsetAsync(out, 0, (size_t)T_TOK * H_DIM * sizeof(float), stream);
        router_kernel<<<256, 256, 0, stream>>>(x, gw, counts, tok, tw);
        gate_up_f32<<<dim3(11, 16, 9), 256, 0, stream>>>(x, egw, euw, sgw, suw, counts, tok, tw, h_r, h_s);
        down_f32<<<dim3(16, 16, 9), 256, 0, stream>>>(h_r, h_s, edw, sdw, counts, tok, out);
    }
}

// Round 4
// 419.723 us; speedup vs baseline: 1.1385x; 1.1338x over previous
//
#include <hip/hip_runtime.h>
#include <hip/hip_bf16.h>

typedef unsigned short u16;
typedef __bf16 bf16x8 __attribute__((ext_vector_type(8)));
typedef float f32x4 __attribute__((ext_vector_type(4)));

#define H_DIM 2048
#define I_DIM 1408
#define T_TOK 1024
#define NEXP 8
#define LS 40  // fallback-path LDS stride

__device__ __forceinline__ u16 f2bf(float f) {
    union { float f; unsigned u; } v; v.f = f;
    unsigned r = v.u + 0x7FFFu + ((v.u >> 16) & 1u);  // RNE
    return (u16)(r >> 16);
}
__device__ __forceinline__ unsigned pack2(float a, float b) {
    float2 t; t.x = a; t.y = b;
    __hip_bfloat162 h = __float22bfloat162_rn(t);  // v_cvt_pk_bf16_f32
    union { __hip_bfloat162 h; unsigned u; } v; v.h = h;
    return v.u;
}
__device__ __forceinline__ uint2 pack4(float4 f) {
    uint2 r; r.x = pack2(f.x, f.y); r.y = pack2(f.z, f.w); return r;
}
__device__ __forceinline__ void g2l16(const void* g, void* l) {
    __builtin_amdgcn_global_load_lds((const __attribute__((address_space(1))) void*)g,
                                     (__attribute__((address_space(3))) void*)l, 16, 0, 0);
}
__device__ __forceinline__ float4 ntload4(const float4* p) {
    const f32x4* q = (const f32x4*)p;            // native clang vector type
    f32x4 v = __builtin_nontemporal_load(q);
    float4 r; r.x = v[0]; r.y = v[1]; r.z = v[2]; r.w = v[3];
    return r;
}

// ============ prep1: convert gate/up weights (lane-contiguous) + router/x-convert ============
// blocks 0..1583: weight convert (egw 704, euw 704, sgw 88, suw 88; 8192 float4 per block)
// blocks 1584..1839: router (4 tokens/block)
struct Prep1Args {
    const float* src[4]; u16* dst[4];
    const float* x; const float* gw; u16* xb;
    int* counts; int* tok; float* tw; unsigned* tslot;
};

__global__ __launch_bounds__(256)
void prep1_kernel(Prep1Args a) {
    int b = blockIdx.x;
    if (b < 1584) {
        int r, rb;
        if (b < 704)       { r = 0; rb = b; }
        else if (b < 1408) { r = 1; rb = b - 704; }
        else if (b < 1496) { r = 2; rb = b - 1408; }
        else               { r = 3; rb = b - 1496; }
        const float4* in = (const float4*)a.src[r];
        uint2* out = (uint2*)a.dst[r];
        size_t base = (size_t)rb * 8192 + threadIdx.x;
#pragma unroll
        for (int it = 0; it < 4; it++) {
            float4 v[8];
#pragma unroll
            for (int j = 0; j < 8; j++) v[j] = ntload4(&in[base + it * 2048 + j * 256]);
#pragma unroll
            for (int j = 0; j < 8; j++) out[base + it * 2048 + j * 256] = pack4(v[j]);
        }
    } else {
        int wave = threadIdx.x >> 6, lane = threadIdx.x & 63;
        int t = (b - 1584) * 4 + wave;
        const float4* xr = (const float4*)(a.x + (size_t)t * H_DIM);
        const float4* gw4 = (const float4*)a.gw;
        uint2* xbr = (uint2*)(a.xb + (size_t)t * H_DIM);
        float acc[NEXP];
#pragma unroll
        for (int e = 0; e < NEXP; e++) acc[e] = 0.f;
#pragma unroll
        for (int j = 0; j < 8; j++) {
            int c = lane + j * 64;
            float4 xv = xr[c];
            xbr[c] = pack4(xv);
#pragma unroll
            for (int e = 0; e < NEXP; e++) {
                float4 gv = gw4[e * 512 + c];
                acc[e] += xv.x * gv.x + xv.y * gv.y + xv.z * gv.z + xv.w * gv.w;
            }
        }
#pragma unroll
        for (int e = 0; e < NEXP; e++) {
#pragma unroll
            for (int off = 32; off > 0; off >>= 1) acc[e] += __shfl_xor(acc[e], off);
        }
        if (lane == 0) {
            int i0 = 0; float v0 = acc[0];
#pragma unroll
            for (int e = 1; e < NEXP; e++) if (acc[e] > v0) { v0 = acc[e]; i0 = e; }
            int i1 = -1; float v1 = -3.0e38f;
#pragma unroll
            for (int e = 0; e < NEXP; e++) if (e != i0 && acc[e] > v1) { v1 = acc[e]; i1 = e; }
            float ex = __expf(v1 - v0);
            float w0 = 1.f / (1.f + ex);
            float w1 = 1.f - w0;
            int s0 = atomicAdd(&a.counts[i0], 1);
            a.tok[i0 * T_TOK + s0] = t; a.tw[i0 * T_TOK + s0] = w0;
            a.tslot[t * 2] = ((unsigned)i0 << 16) | (unsigned)s0;
            int s1 = atomicAdd(&a.counts[i1], 1);
            a.tok[i1 * T_TOK + s1] = t; a.tw[i1 * T_TOK + s1] = w1;
            a.tslot[t * 2 + 1] = ((unsigned)i1 << 16) | (unsigned)s1;
        }
    }
}

// ============ gate+up GEMM (z<9) + down-weight convert (z==9) ============
// m97-geometry: 256 threads / 4 waves (2x2); block 128Mx64N; wave 64Mx32N (per matrix);
// BK=64; single-buffer 32KB XOR-swizzled LDS; 3 blocks/CU.
#define EDW_F4 5767168
__global__ __launch_bounds__(256, 3)
void gate_up_bf(const u16* __restrict__ xb,
                const u16* __restrict__ egb, const u16* __restrict__ eub,
                const u16* __restrict__ sgb, const u16* __restrict__ sub,
                const int* __restrict__ counts, const int* __restrict__ tok,
                const float* __restrict__ tw,
                u16* __restrict__ h_r, u16* __restrict__ h_s,
                const float* __restrict__ edw_f, const float* __restrict__ sdw_f,
                u16* __restrict__ edb, u16* __restrict__ sdb) {
    int e = blockIdx.z;
    if (e == 9) {  // convert edw/sdw -> bf16, overlapped with the GEMM blocks
        int b = blockIdx.y * 22 + blockIdx.x;           // 0..175
        size_t base = (size_t)b * 36864 + threadIdx.x;  // 176*36864 = 6488064 f4 exact
        const float4* ein = (const float4*)edw_f;
        const float4* sin_ = (const float4*)sdw_f;
        uint2* eout = (uint2*)edb;
        uint2* sout = (uint2*)sdb;
        for (int it = 0; it < 18; it++) {
            size_t g0 = base + (size_t)it * 2048;
            float4 v[8];
#pragma unroll
            for (int j = 0; j < 8; j++) {
                size_t g = g0 + j * 256;
                v[j] = (g < EDW_F4) ? ntload4(&ein[g]) : ntload4(&sin_[g - EDW_F4]);
            }
#pragma unroll
            for (int j = 0; j < 8; j++) {
                size_t g = g0 + j * 256;
                if (g < EDW_F4) eout[g] = pack4(v[j]);
                else            sout[g - EDW_F4] = pack4(v[j]);
            }
        }
        return;
    }

    __shared__ u16 lA[128 * 64];   // 16 KB
    __shared__ u16 lG[64 * 64];    // 8 KB
    __shared__ u16 lU[64 * 64];    // 8 KB -> 32 KB total

    bool routed = (e < NEXP);
    int cnt, hbase; const u16 *Wg, *Wu; u16* hout;
    if (routed) {
        cnt = counts[e];
        int p = 0;
#pragma unroll
        for (int i = 0; i < NEXP; i++) { int c = counts[i]; if (i < e) p += c; }
        hbase = p;
        Wg = egb + (size_t)e * I_DIM * H_DIM;
        Wu = eub + (size_t)e * I_DIM * H_DIM;
        hout = h_r;
    } else { cnt = T_TOK; hbase = 0; Wg = sgb; Wu = sub; hout = h_s; }
    int m0 = blockIdx.y * 128;
    if (m0 >= cnt) return;
    int n0 = blockIdx.x * 64;

    int tid = threadIdx.x, lane = tid & 63, w = tid >> 6;
    int wr = w >> 1, wc = w & 1;

    // A: 1024 chunks (128 rows x 8); wave w instr j<4 covers chunks [w*256+j*64, +64)
    const u16* aptr[4]; int aoff[4];
#pragma unroll
    for (int j = 0; j < 4; j++) {
        int chunk = w * 256 + j * 64 + lane;
        int row = chunk >> 3, cl = chunk & 7;
        int cg = cl ^ (row & 7);
        int trow = m0 + row; if (trow > cnt - 1) trow = cnt - 1;
        int tix = routed ? tok[e * T_TOK + trow] : trow;
        aptr[j] = xb + (size_t)tix * H_DIM + cg * 8;
        aoff[j] = (w * 256 + j * 64) * 8;
    }
    // G/U: 512 chunks each (64 rows x 8); wave w instr j<2 covers [w*128+j*64, +64)
    const u16* gptr[2]; const u16* uptr[2]; int goff[2];
#pragma unroll
    for (int j = 0; j < 2; j++) {
        int chunk = w * 128 + j * 64 + lane;
        int row = chunk >> 3, cl = chunk & 7;
        int cg = cl ^ (row & 7);
        gptr[j] = Wg + (size_t)(n0 + row) * H_DIM + cg * 8;
        uptr[j] = Wu + (size_t)(n0 + row) * H_DIM + cg * 8;
        goff[j] = (w * 128 + j * 64) * 8;
    }

    f32x4 zero = {0.f, 0.f, 0.f, 0.f};
    f32x4 accg[4][2], accu[4][2];
#pragma unroll
    for (int a = 0; a < 4; a++)
#pragma unroll
        for (int b = 0; b < 2; b++) { accg[a][b] = zero; accu[a][b] = zero; }

    int r16 = lane & 15, q = lane >> 4;

    for (int k0 = 0; k0 < H_DIM; k0 += 64) {
#pragma unroll
        for (int j = 0; j < 4; j++) g2l16(aptr[j] + k0, &lA[aoff[j]]);
#pragma unroll
        for (int j = 0; j < 2; j++) { g2l16(gptr[j] + k0, &lG[goff[j]]); g2l16(uptr[j] + k0, &lU[goff[j]]); }
        __syncthreads();
#pragma unroll
        for (int kh = 0; kh < 2; kh++) {
            bf16x8 af[4], gf[2], uf[2];
#pragma unroll
            for (int mi = 0; mi < 4; mi++) {
                int row = wr * 64 + mi * 16 + r16;
                int ch = (kh * 4 + q) ^ (row & 7);
                af[mi] = *(const bf16x8*)&lA[row * 64 + ch * 8];
            }
#pragma unroll
            for (int ni = 0; ni < 2; ni++) {
                int row = wc * 32 + ni * 16 + r16;
                int ch = (kh * 4 + q) ^ (row & 7);
                gf[ni] = *(const bf16x8*)&lG[row * 64 + ch * 8];
                uf[ni] = *(const bf16x8*)&lU[row * 64 + ch * 8];
            }
#pragma unroll
            for (int mi = 0; mi < 4; mi++)
#pragma unroll
                for (int ni = 0; ni < 2; ni++) {
                    accg[mi][ni] = __builtin_amdgcn_mfma_f32_16x16x32_bf16(af[mi], gf[ni], accg[mi][ni], 0, 0, 0);
                    accu[mi][ni] = __builtin_amdgcn_mfma_f32_16x16x32_bf16(af[mi], uf[ni], accu[mi][ni], 0, 0, 0);
                }
        }
        __syncthreads();
    }

    // epilogue: C/D col=lane&15, row=(lane>>4)*4+reg
#pragma unroll
    for (int mi = 0; mi < 4; mi++) {
#pragma unroll
        for (int r = 0; r < 4; r++) {
            int row = wr * 64 + mi * 16 + q * 4 + r;
            int gr = m0 + row;
            if (gr < cnt) {
                float wt = routed ? tw[e * T_TOK + gr] : 1.0f;
                u16* hrow = hout + (size_t)(hbase + gr) * I_DIM + n0 + wc * 32;
#pragma unroll
                for (int ni = 0; ni < 2; ni++) {
                    float g = accg[mi][ni][r], u = accu[mi][ni][r];
                    hrow[ni * 16 + r16] = f2bf((g / (1.f + __expf(-g))) * u * wt);
                }
            }
        }
    }
}

// ============ down GEMM: m97-exact 128Mx128N, 4 waves (2x2), wave 64x64, BK=64 ============
__global__ __launch_bounds__(256, 3)
void down_bf(const u16* __restrict__ h_r, const u16* __restrict__ h_s,
             const u16* __restrict__ edb, const u16* __restrict__ sdb,
             const int* __restrict__ counts, const int* __restrict__ tok,
             float* __restrict__ y_r, float* __restrict__ y_s) {
    __shared__ u16 lA[128 * 64];   // 16 KB
    __shared__ u16 lB[128 * 64];   // 16 KB -> 32 KB total

    int e = blockIdx.z;
    bool routed = (e < NEXP);
    int cnt, hbase; const u16* Wd; const u16* hin;
    if (routed) {
        cnt = counts[e];
        int p = 0;
#pragma unroll
        for (int i = 0; i < NEXP; i++) { int c = counts[i]; if (i < e) p += c; }
        hbase = p;
        Wd = edb + (size_t)e * H_DIM * I_DIM;
        hin = h_r;
    } else { cnt = T_TOK; hbase = 0; Wd = sdb; hin = h_s; }
    int m0 = blockIdx.y * 128;
    if (m0 >= cnt) return;
    int n0 = blockIdx.x * 128;

    int tid = threadIdx.x, lane = tid & 63, w = tid >> 6;
    int wr = w >> 1, wc = w & 1;

    const u16* aptr[4]; int aoff[4];
#pragma unroll
    for (int j = 0; j < 4; j++) {
        int chunk = w * 256 + j * 64 + lane;
        int row = chunk >> 3, cl = chunk & 7;
        int cg = cl ^ (row & 7);
        int hr = m0 + row; if (hr > cnt - 1) hr = cnt - 1;
        aptr[j] = hin + (size_t)(hbase + hr) * I_DIM + cg * 8;
        aoff[j] = (w * 256 + j * 64) * 8;
    }
    const u16* bptr[4]; int boff[4];
#pragma unroll
    for (int j = 0; j < 4; j++) {
        int chunk = w * 256 + j * 64 + lane;
        int row = chunk >> 3, cl = chunk & 7;
        int cg = cl ^ (row & 7);
        bptr[j] = Wd + (size_t)(n0 + row) * I_DIM + cg * 8;
        boff[j] = (w * 256 + j * 64) * 8;
    }

    f32x4 zero = {0.f, 0.f, 0.f, 0.f};
    f32x4 acc[4][4];
#pragma unroll
    for (int a = 0; a < 4; a++)
#pragma unroll
        for (int b = 0; b < 4; b++) acc[a][b] = zero;

    int r16 = lane & 15, q = lane >> 4;

    for (int k0 = 0; k0 < I_DIM; k0 += 64) {  // 1408 = 22*64
#pragma unroll
        for (int j = 0; j < 4; j++) g2l16(aptr[j] + k0, &lA[aoff[j]]);
#pragma unroll
        for (int j = 0; j < 4; j++) g2l16(bptr[j] + k0, &lB[boff[j]]);
        __syncthreads();
#pragma unroll
        for (int kh = 0; kh < 2; kh++) {
            bf16x8 af[4], bfr[4];
#pragma unroll
            for (int mi = 0; mi < 4; mi++) {
                int row = wr * 64 + mi * 16 + r16;
                int ch = (kh * 4 + q) ^ (row & 7);
                af[mi] = *(const bf16x8*)&lA[row * 64 + ch * 8];
            }
#pragma unroll
            for (int ni = 0; ni < 4; ni++) {
                int row = wc * 64 + ni * 16 + r16;
                int ch = (kh * 4 + q) ^ (row & 7);
                bfr[ni] = *(const bf16x8*)&lB[row * 64 + ch * 8];
            }
#pragma unroll
            for (int mi = 0; mi < 4; mi++)
#pragma unroll
                for (int ni = 0; ni < 4; ni++)
                    acc[mi][ni] = __builtin_amdgcn_mfma_f32_16x16x32_bf16(af[mi], bfr[ni], acc[mi][ni], 0, 0, 0);
        }
        __syncthreads();
    }

#pragma unroll
    for (int mi = 0; mi < 4; mi++) {
#pragma unroll
        for (int r = 0; r < 4; r++) {
            int row = wr * 64 + mi * 16 + q * 4 + r;
            int gr = m0 + row;
            if (gr < cnt) {
                float* yrow = (routed ? y_r + (size_t)(hbase + gr) * H_DIM
                                      : y_s + (size_t)gr * H_DIM) + n0 + wc * 64;
#pragma unroll
                for (int ni = 0; ni < 4; ni++)
                    yrow[ni * 16 + r16] = acc[mi][ni][r];
            }
        }
    }
}

// ============ reduce: out[t] = y_s[t] + y_r[slot0(t)] + y_r[slot1(t)] ============
__global__ __launch_bounds__(256)
void reduce_kernel(const int* __restrict__ counts, const unsigned* __restrict__ tslot,
                   const float* __restrict__ y_r, const float* __restrict__ y_s,
                   float* __restrict__ out) {
    int t = blockIdx.x;
    int pre[NEXP]; int run = 0;
#pragma unroll
    for (int i = 0; i < NEXP; i++) { pre[i] = run; run += counts[i]; }
    unsigned t0 = tslot[t * 2], t1 = tslot[t * 2 + 1];
    int r0 = pre[t0 >> 16] + (int)(t0 & 0xffffu);
    int r1 = pre[t1 >> 16] + (int)(t1 & 0xffffu);
    const float4* ys = (const float4*)(y_s + (size_t)t * H_DIM);
    const float4* a0 = (const float4*)(y_r + (size_t)r0 * H_DIM);
    const float4* a1 = (const float4*)(y_r + (size_t)r1 * H_DIM);
    float4* o = (float4*)(out + (size_t)t * H_DIM);
#pragma unroll
    for (int j = 0; j < 2; j++) {
        int c = threadIdx.x + j * 256;  // 512 float4 per row
        float4 s = ys[c], b0 = a0[c], b1 = a1[c];
        float4 r;
        r.x = s.x + b0.x + b1.x; r.y = s.y + b0.y + b1.y;
        r.z = s.z + b0.z + b1.z; r.w = s.w + b0.w + b1.w;
        o[c] = r;
    }
}

// ================= FALLBACK PATH (fp32, only if ws too small) =================
__global__ __launch_bounds__(256)
void router_kernel(const float* __restrict__ x, const float* __restrict__ gw,
                   int* __restrict__ counts, int* __restrict__ tok, float* __restrict__ tw) {
    int wave = threadIdx.x >> 6;
    int lane = threadIdx.x & 63;
    int t = blockIdx.x * 4 + wave;
    const float* xr = x + (size_t)t * H_DIM;
    float acc[NEXP];
#pragma unroll
    for (int e = 0; e < NEXP; e++) acc[e] = 0.f;
    for (int h = lane; h < H_DIM; h += 64) {
        float xv = xr[h];
#pragma unroll
        for (int e = 0; e < NEXP; e++) acc[e] += xv * gw[e * H_DIM + h];
    }
#pragma unroll
    for (int e = 0; e < NEXP; e++) {
#pragma unroll
        for (int off = 32; off > 0; off >>= 1) acc[e] += __shfl_xor(acc[e], off);
    }
    if (lane == 0) {
        int i0 = 0; float v0 = acc[0];
#pragma unroll
        for (int e = 1; e < NEXP; e++) if (acc[e] > v0) { v0 = acc[e]; i0 = e; }
        int i1 = -1; float v1 = -3.0e38f;
#pragma unroll
        for (int e = 0; e < NEXP; e++) if (e != i0 && acc[e] > v1) { v1 = acc[e]; i1 = e; }
        float ex = __expf(v1 - v0);
        float w0 = 1.f / (1.f + ex);
        float w1 = 1.f - w0;
        int s0 = atomicAdd(&counts[i0], 1);
        tok[i0 * T_TOK + s0] = t; tw[i0 * T_TOK + s0] = w0;
        int s1 = atomicAdd(&counts[i1], 1);
        tok[i1 * T_TOK + s1] = t; tw[i1 * T_TOK + s1] = w1;
    }
}

__global__ __launch_bounds__(256, 2)
void gate_up_f32(const float* __restrict__ x,
                 const float* __restrict__ egw, const float* __restrict__ euw,
                 const float* __restrict__ sgw, const float* __restrict__ suw,
                 const int* __restrict__ counts, const int* __restrict__ tok,
                 const float* __restrict__ tw,
                 u16* __restrict__ h_r, u16* __restrict__ h_s) {
    __shared__ u16 lA[64 * LS];
    __shared__ u16 lG[128 * LS];
    __shared__ u16 lU[128 * LS];
    int e = blockIdx.z;
    bool routed = (e < NEXP);
    int cnt, hbase; const float *Wg, *Wu; u16* hout;
    if (routed) {
        cnt = counts[e];
        int p = 0;
#pragma unroll
        for (int i = 0; i < NEXP; i++) { int c = counts[i]; if (i < e) p += c; }
        hbase = p;
        Wg = egw + (size_t)e * I_DIM * H_DIM; Wu = euw + (size_t)e * I_DIM * H_DIM; hout = h_r;
    } else { cnt = T_TOK; hbase = 0; Wg = sgw; Wu = suw; hout = h_s; }
    int m0 = blockIdx.y * 64;
    if (m0 >= cnt) return;
    int n0 = blockIdx.x * 128;
    int tid = threadIdx.x, lane = tid & 63, w = tid >> 6;
    const float* ap[2]; int sa[2];
#pragma unroll
    for (int i = 0; i < 2; i++) {
        int slot = tid + i * 256;
        int row = slot >> 3, c4 = slot & 7;
        sa[i] = row * LS + c4 * 4;
        int trow = m0 + row; if (trow > cnt - 1) trow = cnt - 1;
        int tix = routed ? tok[e * T_TOK + trow] : trow;
        ap[i] = x + (size_t)tix * H_DIM + c4 * 4;
    }
    const float* gp[4]; const float* up[4]; int sg[4];
#pragma unroll
    for (int i = 0; i < 4; i++) {
        int slot = tid + i * 256;
        int row = slot >> 3, c4 = slot & 7;
        sg[i] = row * LS + c4 * 4;
        gp[i] = Wg + (size_t)(n0 + row) * H_DIM + c4 * 4;
        up[i] = Wu + (size_t)(n0 + row) * H_DIM + c4 * 4;
    }
    f32x4 zero = {0.f, 0.f, 0.f, 0.f};
    f32x4 accg[4][2], accu[4][2];
#pragma unroll
    for (int a = 0; a < 4; a++)
#pragma unroll
        for (int b = 0; b < 2; b++) { accg[a][b] = zero; accu[a][b] = zero; }
    int r16 = lane & 15, kq = lane >> 4;
    float4 ra[2], rg[4], ru[4];
#pragma unroll
    for (int i = 0; i < 2; i++) ra[i] = *(const float4*)(ap[i]);
#pragma unroll
    for (int i = 0; i < 4; i++) { rg[i] = *(const float4*)(gp[i]); ru[i] = *(const float4*)(up[i]); }
    for (int k0 = 0; k0 < H_DIM; k0 += 32) {
#pragma unroll
        for (int i = 0; i < 2; i++) *(uint2*)&lA[sa[i]] = pack4(ra[i]);
#pragma unroll
        for (int i = 0; i < 4; i++) { *(uint2*)&lG[sg[i]] = pack4(rg[i]); *(uint2*)&lU[sg[i]] = pack4(ru[i]); }
        __syncthreads();
        if (k0 + 32 < H_DIM) {
            int kn = k0 + 32;
#pragma unroll
            for (int i = 0; i < 2; i++) ra[i] = *(const float4*)(ap[i] + kn);
#pragma unroll
            for (int i = 0; i < 4; i++) { rg[i] = *(const float4*)(gp[i] + kn); ru[i] = *(const float4*)(up[i] + kn); }
        }
        bf16x8 af[4], gf[2], uf[2];
#pragma unroll
        for (int mi = 0; mi < 4; mi++) af[mi] = *(const bf16x8*)&lA[(mi * 16 + r16) * LS + kq * 8];
#pragma unroll
        for (int ni = 0; ni < 2; ni++) {
            gf[ni] = *(const bf16x8*)&lG[(w * 32 + ni * 16 + r16) * LS + kq * 8];
            uf[ni] = *(const bf16x8*)&lU[(w * 32 + ni * 16 + r16) * LS + kq * 8];
        }
#pragma unroll
        for (int mi = 0; mi < 4; mi++)
#pragma unroll
            for (int ni = 0; ni < 2; ni++) {
                accg[mi][ni] = __builtin_amdgcn_mfma_f32_16x16x32_bf16(af[mi], gf[ni], accg[mi][ni], 0, 0, 0);
                accu[mi][ni] = __builtin_amdgcn_mfma_f32_16x16x32_bf16(af[mi], uf[ni], accu[mi][ni], 0, 0, 0);
            }
        __syncthreads();
    }
#pragma unroll
    for (int mi = 0; mi < 4; mi++) {
#pragma unroll
        for (int r = 0; r < 4; r++) {
            int row = mi * 16 + kq * 4 + r;
            int gr = m0 + row;
            if (gr < cnt) {
                float wt = routed ? tw[e * T_TOK + gr] : 1.0f;
                u16* hrow = hout + (size_t)(hbase + gr) * I_DIM + n0 + w * 32;
#pragma unroll
                for (int ni = 0; ni < 2; ni++) {
                    float g = accg[mi][ni][r], u = accu[mi][ni][r];
                    hrow[ni * 16 + r16] = f2bf((g / (1.f + __expf(-g))) * u * wt);
                }
            }
        }
    }
}

__global__ __launch_bounds__(256, 2)
void down_f32(const u16* __restrict__ h_r, const u16* __restrict__ h_s,
              const float* __restrict__ edw, const float* __restrict__ sdw,
              const int* __restrict__ counts, const int* __restrict__ tok,
              float* __restrict__ out) {
    __shared__ u16 lA[64 * LS];
    __shared__ u16 lB[128 * LS];
    int e = blockIdx.z;
    bool routed = (e < NEXP);
    int cnt, hbase; const float* Wd; const u16* hin;
    if (routed) {
        cnt = counts[e];
        int p = 0;
#pragma unroll
    for (int i = 0; i < NEXP; i++) { int c = counts[i]; if (i < e) p += c; }
        hbase = p;
        Wd = edw + (size_t)e * H_DIM * I_DIM; hin = h_r;
    } else { cnt = T_TOK; hbase = 0; Wd = sdw; hin = h_s; }
    int m0 = blockIdx.y * 64;
    if (m0 >= cnt) return;
    int n0 = blockIdx.x * 128;
    int tid = threadIdx.x, lane = tid & 63, w = tid >> 6;
    int arow = tid >> 2, ac8 = tid & 3;
    int hr = m0 + arow; if (hr > cnt - 1) hr = cnt - 1;
    const u16* ap = hin + (size_t)(hbase + hr) * I_DIM + ac8 * 8;
    int sa = arow * LS + ac8 * 8;
    const float* bp[4]; int sb[4];
#pragma unroll
    for (int i = 0; i < 4; i++) {
        int slot = tid + i * 256;
        int row = slot >> 3, c4 = slot & 7;
        bp[i] = Wd + (size_t)(n0 + row) * I_DIM + c4 * 4;
        sb[i] = row * LS + c4 * 4;
    }
    f32x4 zero = {0.f, 0.f, 0.f, 0.f};
    f32x4 acc[4][2];
#pragma unroll
    for (int a = 0; a < 4; a++)
#pragma unroll
        for (int b = 0; b < 2; b++) acc[a][b] = zero;
    int r16 = lane & 15, kq = lane >> 4;
    uint4 ra = *(const uint4*)(ap);
    float4 rb[4];
#pragma unroll
    for (int i = 0; i < 4; i++) rb[i] = *(const float4*)(bp[i]);
    for (int k0 = 0; k0 < I_DIM; k0 += 32) {
        *(uint4*)&lA[sa] = ra;
#pragma unroll
        for (int i = 0; i < 4; i++) *(uint2*)&lB[sb[i]] = pack4(rb[i]);
        __syncthreads();
        if (k0 + 32 < I_DIM) {
            int kn = k0 + 32;
            ra = *(const uint4*)(ap + kn);
#pragma unroll
            for (int i = 0; i < 4; i++) rb[i] = *(const float4*)(bp[i] + kn);
        }
        bf16x8 af[4], bfr[2];
#pragma unroll
        for (int mi = 0; mi < 4; mi++) af[mi] = *(const bf16x8*)&lA[(mi * 16 + r16) * LS + kq * 8];
#pragma unroll
        for (int ni = 0; ni < 2; ni++) bfr[ni] = *(const bf16x8*)&lB[(w * 32 + ni * 16 + r16) * LS + kq * 8];
#pragma unroll
        for (int mi = 0; mi < 4; mi++)
#pragma unroll
            for (int ni = 0; ni < 2; ni++)
                acc[mi][ni] = __builtin_amdgcn_mfma_f32_16x16x32_bf16(af[mi], bfr[ni], acc[mi][ni], 0, 0, 0);
        __syncthreads();
    }
#pragma unroll
    for (int mi = 0; mi < 4; mi++) {
#pragma unroll
        for (int r = 0; r < 4; r++) {
            int row = mi * 16 + kq * 4 + r;
            int gr = m0 + row;
            if (gr < cnt) {
                int t = routed ? tok[e * T_TOK + gr] : gr;
                float* orow = out + (size_t)t * H_DIM + n0 + w * 32;
#pragma unroll
                for (int ni = 0; ni < 2; ni++)
                    atomicAdd(&orow[ni * 16 + r16], acc[mi][ni][r]);
            }
        }
    }
}

extern "C" void kernel_launch(void* const* d_in, const int* in_sizes, int n_in,
                              void* d_out, int out_size, void* d_ws, size_t ws_size,
                              hipStream_t stream) {
    const float* x   = (const float*)d_in[0];
    const float* gw  = (const float*)d_in[1];
    const float* egw = (const float*)d_in[2];
    const float* euw = (const float*)d_in[3];
    const float* edw = (const float*)d_in[4];
    const float* sgw = (const float*)d_in[5];
    const float* suw = (const float*)d_in[6];
    const float* sdw = (const float*)d_in[7];
    float* out = (float*)d_out;

    char* ws = (char*)d_ws;
    int*      counts = (int*)ws;                  // 32 B
    int*      tok    = (int*)(ws + 256);          // 32 KB
    float*    tw     = (float*)(ws + 33024);      // 32 KB
    unsigned* tslot  = (unsigned*)(ws + 65792);   // 8 KB
    u16*      h_r    = (u16*)(ws + 73984);        // 5767168 B
    u16*      h_s    = (u16*)(ws + 5841152);      // 2883584 B
    u16*      xb     = (u16*)(ws + 8724736);      // 4194304 B
    u16*      egb    = (u16*)(ws + 12919040);     // 46137344 B
    u16*      eub    = (u16*)(ws + 59056384);     // 46137344 B
    u16*      edb    = (u16*)(ws + 105193728);    // 46137344 B
    u16*      sgb    = (u16*)(ws + 151331072);    // 5767168 B
    u16*      sub    = (u16*)(ws + 157098240);    // 5767168 B
    u16*      sdb    = (u16*)(ws + 162865408);    // 5767168 B -> end 168632576
    // y buffers overlay egb/eub (dead after gate_up dispatch)
    float*    y_r    = (float*)(ws + 12919040);   // 16777216 B
    float*    y_s    = (float*)(ws + 29696256);   // 8388608 B

    hipMemsetAsync(counts, 0, 32, stream);

    const size_t NEED = 168632576ull;
    if (ws_size >= NEED) {
        Prep1Args pa;
        pa.src[0] = egw; pa.dst[0] = egb;
        pa.src[1] = euw; pa.dst[1] = eub;
        pa.src[2] = sgw; pa.dst[2] = sgb;
        pa.src[3] = suw; pa.dst[3] = sub;
        pa.x = x; pa.gw = gw; pa.xb = xb;
        pa.counts = counts; pa.tok = tok; pa.tw = tw; pa.tslot = tslot;
        prep1_kernel<<<1840, 256, 0, stream>>>(pa);
        // z 0..7 routed, z==8 shared, z==9 edw/sdw bf16 convert (overlapped)
        gate_up_bf<<<dim3(22, 8, 10), 256, 0, stream>>>(xb, egb, eub, sgb, sub, counts, tok, tw,
                                                        h_r, h_s, edw, sdw, edb, sdb);
        down_bf<<<dim3(16, 8, 9), 256, 0, stream>>>(h_r, h_s, edb, sdb, counts, tok, y_r, y_s);
        reduce_kernel<<<1024, 256, 0, stream>>>(counts, tslot, y_r, y_s, out);
    } else {
        hipMemsetAsync(out, 0, (size_t)T_TOK * H_DIM * sizeof(float), stream);
        router_kernel<<<256, 256, 0, stream>>>(x, gw, counts, tok, tw);
        gate_up_f32<<<dim3(11, 16, 9), 256, 0, stream>>>(x, egw, euw, sgw, suw, counts, tok, tw, h_r, h_s);
        down_f32<<<dim3(16, 16, 9), 256, 0, stream>>>(h_r, h_s, edw, sdw, counts, tok, out);
    }
}